// Round 2
// baseline (858.233 us; speedup 1.0000x reference)
//
#include <hip/hip_runtime.h>
#include <hip/hip_bf16.h>

#define NROWS 100000
#define NEDGE 1600000
#define CIN   256
#define COUT  128

typedef __bf16 bf16x8 __attribute__((ext_vector_type(8)));
typedef __bf16 bf16x2 __attribute__((ext_vector_type(2)));
typedef float  floatx4 __attribute__((ext_vector_type(4)));
typedef float  floatx2 __attribute__((ext_vector_type(2)));

// ---------------------------------------------------------------------------
// Kernel 1: feat = (emb .* mask1) @ W^T + b_fc      [NROWS x COUT]
// Inputs f32; MFMA 16x16x32 bf16 internally; feat stored bf16 in ws.
// Block = 256 thr = 4 waves; each wave: 16 rows x 128 cols.
// A-frag: A[m=lane&15][k=(lane>>4)*8+j]
// B-frag: B[k][n=lane&15], k=(lane>>4)*8+j  (W is [COUT][CIN] row-major = B^T)
// C/D:    col=lane&15, row=(lane>>4)*4+reg   [m89-verified layout]
// ---------------------------------------------------------------------------
__global__ __launch_bounds__(256) void gemm_kernel(
    const float* __restrict__ emb, const float* __restrict__ mask1,
    const float* __restrict__ W,   const float* __restrict__ b_fc,
    __bf16* __restrict__ feat)
{
    const int wave = threadIdx.x >> 6;
    const int lane = threadIdx.x & 63;
    const int mrow = lane & 15;
    const int kgrp = lane >> 4;
    const int m0 = blockIdx.x * 64 + wave * 16;

    int mload = m0 + mrow;
    if (mload >= NROWS) mload = NROWS - 1;   // clamp loads; stores guarded
    const float* embp = emb   + (size_t)mload * CIN;
    const float* m1p  = mask1 + (size_t)mload * CIN;

    floatx4 acc[8];
#pragma unroll
    for (int t = 0; t < 8; t++) acc[t] = (floatx4){0.f, 0.f, 0.f, 0.f};

#pragma unroll
    for (int ks = 0; ks < 8; ks++) {
        const int k0 = ks * 32 + kgrp * 8;
        floatx4 e0 = *(const floatx4*)(embp + k0);
        floatx4 e1 = *(const floatx4*)(embp + k0 + 4);
        floatx4 q0 = *(const floatx4*)(m1p  + k0);
        floatx4 q1 = *(const floatx4*)(m1p  + k0 + 4);
        bf16x8 x;
#pragma unroll
        for (int j = 0; j < 4; j++) {
            x[j]     = (__bf16)(e0[j] * q0[j]);
            x[4 + j] = (__bf16)(e1[j] * q1[j]);
        }
#pragma unroll
        for (int t = 0; t < 8; t++) {
            const float* wp = W + (size_t)(t * 16 + mrow) * CIN + k0;
            floatx4 w0 = *(const floatx4*)(wp);
            floatx4 w1 = *(const floatx4*)(wp + 4);
            bf16x8 b;
#pragma unroll
            for (int j = 0; j < 4; j++) {
                b[j]     = (__bf16)w0[j];
                b[4 + j] = (__bf16)w1[j];
            }
            acc[t] = __builtin_amdgcn_mfma_f32_16x16x32_bf16(x, b, acc[t], 0, 0, 0);
        }
    }

#pragma unroll
    for (int t = 0; t < 8; t++) {
        const int col = t * 16 + mrow;
        const float bc = b_fc[col];
#pragma unroll
        for (int r = 0; r < 4; r++) {
            const int row = m0 + kgrp * 4 + r;
            if (row < NROWS)
                feat[(size_t)row * COUT + col] = (__bf16)(acc[t][r] + bc);
        }
    }
}

// ---------------------------------------------------------------------------
// Kernel 2: histogram of rows -> counts[]
// ---------------------------------------------------------------------------
__global__ __launch_bounds__(256) void hist_kernel(
    const int* __restrict__ rows, int* __restrict__ counts)
{
    const int i = blockIdx.x * 256 + threadIdx.x;
    if (i < NEDGE) atomicAdd(&counts[rows[i]], 1);
}

// ---------------------------------------------------------------------------
// Kernel 3: single-block exclusive scan of counts -> row_start[0..NROWS]
// ---------------------------------------------------------------------------
__global__ __launch_bounds__(1024) void scan_kernel(
    const int* __restrict__ counts, int* __restrict__ row_start)
{
    __shared__ int sums[1024];
    const int t = threadIdx.x;
    const int CH = (NROWS + 1023) / 1024;   // 98
    const int begin = t * CH;
    const int end = (begin + CH < NROWS) ? begin + CH : NROWS;

    int s = 0;
    for (int i = begin; i < end; i++) s += counts[i];
    sums[t] = s;
    __syncthreads();

    // Hillis-Steele inclusive scan (read-before-write protected by barriers)
    for (int off = 1; off < 1024; off <<= 1) {
        int v = (t >= off) ? sums[t - off] : 0;
        __syncthreads();
        sums[t] += v;
        __syncthreads();
    }

    int run = (t == 0) ? 0 : sums[t - 1];
    for (int i = begin; i < end; i++) { row_start[i] = run; run += counts[i]; }
    if (t == 1023) row_start[NROWS] = sums[1023];
}

// ---------------------------------------------------------------------------
// Kernel 4: scatter edges into CSR order: (col, val) pairs per row bucket
// ---------------------------------------------------------------------------
__global__ __launch_bounds__(256) void fill_kernel(
    const int* __restrict__ rows, const int* __restrict__ cols,
    const float* __restrict__ vals, const int* __restrict__ row_start,
    int* __restrict__ cursor, int* __restrict__ scol, float* __restrict__ sval)
{
    const int i = blockIdx.x * 256 + threadIdx.x;
    if (i < NEDGE) {
        const int r = rows[i];
        const int pos = row_start[r] + atomicAdd(&cursor[r], 1);
        scol[pos] = cols[i];
        sval[pos] = vals[i];
    }
}

// ---------------------------------------------------------------------------
// Kernel 5: per-row gather-accumulate + fused epilogue (f32 out)
// One wave per row; lane covers 2 adjacent cols (4B feat loads, 8B f32 stores)
// out = prelu((segsum + bias) * mask2)
// ---------------------------------------------------------------------------
__global__ __launch_bounds__(256) void gather_kernel(
    const __bf16* __restrict__ feat, const int* __restrict__ row_start,
    const int* __restrict__ scol, const float* __restrict__ sval,
    const float* __restrict__ bias, const float* __restrict__ mask2,
    const float* __restrict__ prelu_a, float* __restrict__ out)
{
    const int wave = threadIdx.x >> 6;
    const int lane = threadIdx.x & 63;
    const int row = blockIdx.x * 4 + wave;
    if (row >= NROWS) return;

    const int s = row_start[row];
    const int e = row_start[row + 1];
    const int c2 = lane * 2;

    float acc0 = 0.f, acc1 = 0.f;
    for (int k = s; k < e; k++) {
        const int c = scol[k];
        const float v = sval[k];
        bf16x2 h = *(const bf16x2*)(feat + (size_t)c * COUT + c2);
        acc0 += v * (float)h[0];
        acc1 += v * (float)h[1];
    }

    const float a = prelu_a[0];
    floatx2 b = *(const floatx2*)(bias + c2);
    floatx2 m = *(const floatx2*)(mask2 + (size_t)row * COUT + c2);
    float o0 = (acc0 + b[0]) * m[0];
    float o1 = (acc1 + b[1]) * m[1];
    o0 = (o0 > 0.f) ? o0 : a * o0;
    o1 = (o1 > 0.f) ? o1 : a * o1;
    floatx2 o;
    o[0] = o0;
    o[1] = o1;
    *(floatx2*)(out + (size_t)row * COUT + c2) = o;
}

// ---------------------------------------------------------------------------
extern "C" void kernel_launch(void* const* d_in, const int* in_sizes, int n_in,
                              void* d_out, int out_size, void* d_ws, size_t ws_size,
                              hipStream_t stream)
{
    const float* emb     = (const float*)d_in[0];
    const float* vals    = (const float*)d_in[1];
    const float* W       = (const float*)d_in[2];
    const float* b_fc    = (const float*)d_in[3];
    const float* bias    = (const float*)d_in[4];
    const float* prelu_a = (const float*)d_in[5];
    const float* mask1   = (const float*)d_in[6];
    const float* mask2   = (const float*)d_in[7];
    const int*   rows    = (const int*)d_in[8];
    const int*   cols    = (const int*)d_in[9];

    char* ws = (char*)d_ws;
    // ws layout (16B-aligned partitions)
    __bf16* feat      = (__bf16*)(ws);                       // 25,600,000 B
    int*    counts    = (int*)(ws + 25600000);               //    400,000 B
    int*    cursor    = (int*)(ws + 26000000);               //    400,000 B
    int*    row_start = (int*)(ws + 26400000);               //    400,004 B
    int*    scol      = (int*)(ws + 26800016);               //  6,400,000 B
    float*  sval      = (float*)(ws + 33200016);             //  6,400,000 B
    // total ~39.6 MB

    // zero counts + cursor (contiguous 800,000 B)
    hipMemsetAsync(ws + 25600000, 0, 800000, stream);

    gemm_kernel<<<(NROWS + 63) / 64, 256, 0, stream>>>(emb, mask1, W, b_fc, feat);
    hist_kernel<<<NEDGE / 256, 256, 0, stream>>>(rows, counts);
    scan_kernel<<<1, 1024, 0, stream>>>(counts, row_start);
    fill_kernel<<<NEDGE / 256, 256, 0, stream>>>(rows, cols, vals, row_start,
                                                 cursor, scol, sval);
    gather_kernel<<<NROWS / 4, 256, 0, stream>>>(feat, row_start, scol, sval,
                                                 bias, mask2, prelu_a,
                                                 (float*)d_out);
}

// Round 3
// 583.290 us; speedup vs baseline: 1.4714x; 1.4714x over previous
//
#include <hip/hip_runtime.h>
#include <hip/hip_bf16.h>

#define NROWS 100000
#define NEDGE 1600000
#define CIN   256
#define COUT  128

typedef __bf16 bf16x8 __attribute__((ext_vector_type(8)));
typedef __bf16 bf16x2 __attribute__((ext_vector_type(2)));
typedef float  floatx4 __attribute__((ext_vector_type(4)));
typedef float  floatx2 __attribute__((ext_vector_type(2)));

// ---------------------------------------------------------------------------
// Kernel 1: feat = (emb .* mask1) @ W^T + b_fc      [NROWS x COUT]
// Inputs f32; MFMA 16x16x32 bf16 internally; feat stored bf16 in ws.
// ---------------------------------------------------------------------------
__global__ __launch_bounds__(256) void gemm_kernel(
    const float* __restrict__ emb, const float* __restrict__ mask1,
    const float* __restrict__ W,   const float* __restrict__ b_fc,
    __bf16* __restrict__ feat)
{
    const int wave = threadIdx.x >> 6;
    const int lane = threadIdx.x & 63;
    const int mrow = lane & 15;
    const int kgrp = lane >> 4;
    const int m0 = blockIdx.x * 64 + wave * 16;

    int mload = m0 + mrow;
    if (mload >= NROWS) mload = NROWS - 1;   // clamp loads; stores guarded
    const float* embp = emb   + (size_t)mload * CIN;
    const float* m1p  = mask1 + (size_t)mload * CIN;

    floatx4 acc[8];
#pragma unroll
    for (int t = 0; t < 8; t++) acc[t] = (floatx4){0.f, 0.f, 0.f, 0.f};

#pragma unroll
    for (int ks = 0; ks < 8; ks++) {
        const int k0 = ks * 32 + kgrp * 8;
        floatx4 e0 = *(const floatx4*)(embp + k0);
        floatx4 e1 = *(const floatx4*)(embp + k0 + 4);
        floatx4 q0 = *(const floatx4*)(m1p  + k0);
        floatx4 q1 = *(const floatx4*)(m1p  + k0 + 4);
        bf16x8 x;
#pragma unroll
        for (int j = 0; j < 4; j++) {
            x[j]     = (__bf16)(e0[j] * q0[j]);
            x[4 + j] = (__bf16)(e1[j] * q1[j]);
        }
#pragma unroll
        for (int t = 0; t < 8; t++) {
            const float* wp = W + (size_t)(t * 16 + mrow) * CIN + k0;
            floatx4 w0 = *(const floatx4*)(wp);
            floatx4 w1 = *(const floatx4*)(wp + 4);
            bf16x8 b;
#pragma unroll
            for (int j = 0; j < 4; j++) {
                b[j]     = (__bf16)w0[j];
                b[4 + j] = (__bf16)w1[j];
            }
            acc[t] = __builtin_amdgcn_mfma_f32_16x16x32_bf16(x, b, acc[t], 0, 0, 0);
        }
    }

#pragma unroll
    for (int t = 0; t < 8; t++) {
        const int col = t * 16 + mrow;
        const float bc = b_fc[col];
#pragma unroll
        for (int r = 0; r < 4; r++) {
            const int row = m0 + kgrp * 4 + r;
            if (row < NROWS)
                feat[(size_t)row * COUT + col] = (__bf16)(acc[t][r] + bc);
        }
    }
}

// ---------------------------------------------------------------------------
// Kernel 2: histogram of rows -> counts[]
// ---------------------------------------------------------------------------
__global__ __launch_bounds__(256) void hist_kernel(
    const int* __restrict__ rows, int* __restrict__ counts)
{
    const int i = blockIdx.x * 256 + threadIdx.x;
    if (i < NEDGE) atomicAdd(&counts[rows[i]], 1);
}

// ---------------------------------------------------------------------------
// Kernels 3a/3b/3c: hierarchical exclusive scan of counts -> row_start
// scan1: 98 blocks x 1024 thr, LDS Hillis-Steele, coalesced loads
// scan2: 1 block scans the 98 block sums (exclusive, in place)
// scan3: add block offsets; row_start[NROWS] = NEDGE (constant)
// ---------------------------------------------------------------------------
__global__ __launch_bounds__(1024) void scan1_kernel(
    const int* __restrict__ counts, int* __restrict__ row_start,
    int* __restrict__ bsum)
{
    __shared__ int s[1024];
    const int t = threadIdx.x;
    const int i = blockIdx.x * 1024 + t;
    const int v = (i < NROWS) ? counts[i] : 0;
    s[t] = v;
    __syncthreads();
    for (int off = 1; off < 1024; off <<= 1) {
        int u = (t >= off) ? s[t - off] : 0;
        __syncthreads();
        s[t] += u;
        __syncthreads();
    }
    if (i < NROWS) row_start[i] = s[t] - v;   // exclusive within block
    if (t == 1023) bsum[blockIdx.x] = s[1023];
}

__global__ __launch_bounds__(128) void scan2_kernel(int* __restrict__ bsum)
{
    __shared__ int s[128];
    const int t = threadIdx.x;
    const int NB = (NROWS + 1023) / 1024;   // 98
    const int v = (t < NB) ? bsum[t] : 0;
    s[t] = v;
    __syncthreads();
    for (int off = 1; off < 128; off <<= 1) {
        int u = (t >= off) ? s[t - off] : 0;
        __syncthreads();
        s[t] += u;
        __syncthreads();
    }
    if (t < NB) bsum[t] = s[t] - v;          // exclusive block offsets
}

__global__ __launch_bounds__(256) void scan3_kernel(
    int* __restrict__ row_start, const int* __restrict__ bsum)
{
    const int i = blockIdx.x * 256 + threadIdx.x;
    if (i < NROWS) row_start[i] += bsum[i >> 10];
    if (i == 0) row_start[NROWS] = NEDGE;
}

// ---------------------------------------------------------------------------
// Kernel 4: scatter edges into CSR order as packed (col, val_bits) int2
// ---------------------------------------------------------------------------
__global__ __launch_bounds__(256) void fill_kernel(
    const int* __restrict__ rows, const int* __restrict__ cols,
    const float* __restrict__ vals, const int* __restrict__ row_start,
    int* __restrict__ cursor, int2* __restrict__ edge)
{
    const int i = blockIdx.x * 256 + threadIdx.x;
    if (i < NEDGE) {
        const int r = rows[i];
        const int pos = row_start[r] + atomicAdd(&cursor[r], 1);
        edge[pos] = make_int2(cols[i], __float_as_int(vals[i]));
    }
}

// ---------------------------------------------------------------------------
// Kernel 5: per-row gather-accumulate + fused epilogue (f32 out)
// One wave per row; lane covers 2 adjacent cols. Edge loop unrolled x4 with
// independent accumulators -> 4 feat loads in flight (latency hiding).
// ---------------------------------------------------------------------------
__global__ __launch_bounds__(256) void gather_kernel(
    const __bf16* __restrict__ feat, const int* __restrict__ row_start,
    const int2* __restrict__ edge,
    const float* __restrict__ bias, const float* __restrict__ mask2,
    const float* __restrict__ prelu_a, float* __restrict__ out)
{
    const int wave = threadIdx.x >> 6;
    const int lane = threadIdx.x & 63;
    const int row = blockIdx.x * 4 + wave;
    if (row >= NROWS) return;

    const int s = __builtin_amdgcn_readfirstlane(row_start[row]);
    const int e = __builtin_amdgcn_readfirstlane(row_start[row + 1]);
    const int c2 = lane * 2;

    float p0 = 0.f, p1 = 0.f, q0 = 0.f, q1 = 0.f;
    float r0 = 0.f, r1 = 0.f, u0 = 0.f, u1 = 0.f;
    int k = s;
    for (; k + 4 <= e; k += 4) {
        const int2 e0 = edge[k],     e1 = edge[k + 1];
        const int2 e2 = edge[k + 2], e3 = edge[k + 3];
        bf16x2 h0 = *(const bf16x2*)(feat + (size_t)e0.x * COUT + c2);
        bf16x2 h1 = *(const bf16x2*)(feat + (size_t)e1.x * COUT + c2);
        bf16x2 h2 = *(const bf16x2*)(feat + (size_t)e2.x * COUT + c2);
        bf16x2 h3 = *(const bf16x2*)(feat + (size_t)e3.x * COUT + c2);
        const float v0 = __int_as_float(e0.y), v1 = __int_as_float(e1.y);
        const float v2 = __int_as_float(e2.y), v3 = __int_as_float(e3.y);
        p0 += v0 * (float)h0[0]; p1 += v0 * (float)h0[1];
        q0 += v1 * (float)h1[0]; q1 += v1 * (float)h1[1];
        r0 += v2 * (float)h2[0]; r1 += v2 * (float)h2[1];
        u0 += v3 * (float)h3[0]; u1 += v3 * (float)h3[1];
    }
    for (; k < e; k++) {
        const int2 e0 = edge[k];
        bf16x2 h0 = *(const bf16x2*)(feat + (size_t)e0.x * COUT + c2);
        const float v0 = __int_as_float(e0.y);
        p0 += v0 * (float)h0[0]; p1 += v0 * (float)h0[1];
    }
    const float acc0 = (p0 + q0) + (r0 + u0);
    const float acc1 = (p1 + q1) + (r1 + u1);

    const float a = prelu_a[0];
    floatx2 b = *(const floatx2*)(bias + c2);
    floatx2 m = *(const floatx2*)(mask2 + (size_t)row * COUT + c2);
    float o0 = (acc0 + b[0]) * m[0];
    float o1 = (acc1 + b[1]) * m[1];
    o0 = (o0 > 0.f) ? o0 : a * o0;
    o1 = (o1 > 0.f) ? o1 : a * o1;
    floatx2 o;
    o[0] = o0;
    o[1] = o1;
    *(floatx2*)(out + (size_t)row * COUT + c2) = o;
}

// ---------------------------------------------------------------------------
extern "C" void kernel_launch(void* const* d_in, const int* in_sizes, int n_in,
                              void* d_out, int out_size, void* d_ws, size_t ws_size,
                              hipStream_t stream)
{
    const float* emb     = (const float*)d_in[0];
    const float* vals    = (const float*)d_in[1];
    const float* W       = (const float*)d_in[2];
    const float* b_fc    = (const float*)d_in[3];
    const float* bias    = (const float*)d_in[4];
    const float* prelu_a = (const float*)d_in[5];
    const float* mask1   = (const float*)d_in[6];
    const float* mask2   = (const float*)d_in[7];
    const int*   rows    = (const int*)d_in[8];
    const int*   cols    = (const int*)d_in[9];

    char* ws = (char*)d_ws;
    // ws layout (16B-aligned partitions), total 39,600,016 B
    __bf16* feat      = (__bf16*)(ws);                       // 25,600,000 B
    int*    counts    = (int*)(ws + 25600000);               //    400,000 B
    int*    cursor    = (int*)(ws + 26000000);               //    400,000 B
    int*    row_start = (int*)(ws + 26400000);               //    400,004 B
    int2*   edge      = (int2*)(ws + 26800016);              // 12,800,000 B
    // bsum aliases the head of `edge`: scan1 writes it, scan2/scan3 read it,
    // and fill_kernel (which overwrites edge) only runs after scan3 in-stream.
    int*    bsum      = (int*)(ws + 26800016);               //        392 B

    // zero counts + cursor (contiguous 800,000 B)
    hipMemsetAsync(ws + 25600000, 0, 800000, stream);

    gemm_kernel<<<(NROWS + 63) / 64, 256, 0, stream>>>(emb, mask1, W, b_fc, feat);
    hist_kernel<<<NEDGE / 256, 256, 0, stream>>>(rows, counts);
    scan1_kernel<<<(NROWS + 1023) / 1024, 1024, 0, stream>>>(counts, row_start, bsum);
    scan2_kernel<<<1, 128, 0, stream>>>(bsum);
    scan3_kernel<<<(NROWS + 255) / 256, 256, 0, stream>>>(row_start, bsum);
    fill_kernel<<<NEDGE / 256, 256, 0, stream>>>(rows, cols, vals, row_start,
                                                 cursor, edge);
    gather_kernel<<<NROWS / 4, 256, 0, stream>>>(feat, row_start, edge,
                                                 bias, mask2, prelu_a,
                                                 (float*)d_out);
}

// Round 5
// 581.343 us; speedup vs baseline: 1.4763x; 1.0033x over previous
//
#include <hip/hip_runtime.h>
#include <hip/hip_bf16.h>

#define NROWS 100000
#define NEDGE 1600000
#define CIN   256
#define COUT  128

typedef __bf16 bf16x8 __attribute__((ext_vector_type(8)));
typedef __bf16 bf16x2 __attribute__((ext_vector_type(2)));
typedef float  floatx4 __attribute__((ext_vector_type(4)));
typedef float  floatx2 __attribute__((ext_vector_type(2)));

// ---------------------------------------------------------------------------
// Kernel 1: feat = (emb .* mask1) @ W^T + b_fc      [NROWS x COUT]
// W staged ONCE per block into LDS as bf16 in fragment-major layout:
//   frag(ks,t), lane l  ->  wlds[((ks*8+t)*64 + l)*8 .. +8]   (64 KB total)
// Every B-fragment read is a stride-1 ds_read_b128 (conflict-free).
// Each wave: 32 rows (2 A-frags) x 128 cols; block = 4 waves = 128 rows.
// A-frag: A[m=lane&15][k=(lane>>4)*8+j]; C/D: col=lane&15, row=(lane>>4)*4+reg
// ---------------------------------------------------------------------------
__global__ __launch_bounds__(256) void gemm_kernel(
    const float* __restrict__ emb, const float* __restrict__ mask1,
    const float* __restrict__ W,   const float* __restrict__ b_fc,
    __bf16* __restrict__ feat)
{
    __shared__ __bf16 wlds[32768];   // 64 KB exactly

    const int tid = threadIdx.x;

    // --- stage W (f32 -> bf16, fragment-major), 16 frags per thread ---
#pragma unroll
    for (int f = tid; f < 4096; f += 256) {
        const int g    = f >> 6;       // ks*8 + t
        const int l8   = f & 63;       // lane within frag
        const int ks   = g >> 3;
        const int t    = g & 7;
        const int mr   = l8 & 15;
        const int kg   = l8 >> 4;
        const float* wp = W + (size_t)(t * 16 + mr) * CIN + ks * 32 + kg * 8;
        floatx4 w0 = *(const floatx4*)(wp);
        floatx4 w1 = *(const floatx4*)(wp + 4);
        bf16x8 b;
#pragma unroll
        for (int j = 0; j < 4; j++) {
            b[j]     = (__bf16)w0[j];
            b[4 + j] = (__bf16)w1[j];
        }
        *(bf16x8*)(wlds + (size_t)f * 8) = b;
    }
    __syncthreads();

    const int wave = tid >> 6;
    const int lane = tid & 63;
    const int mrow = lane & 15;
    const int kgrp = lane >> 4;
    const int m0 = blockIdx.x * 128 + wave * 32;

    int mA = m0 + mrow;
    int mB = m0 + 16 + mrow;
    if (mA >= NROWS) mA = NROWS - 1;   // clamp loads; stores guarded
    if (mB >= NROWS) mB = NROWS - 1;
    const float* ea = emb   + (size_t)mA * CIN;
    const float* qa = mask1 + (size_t)mA * CIN;
    const float* eb = emb   + (size_t)mB * CIN;
    const float* qb = mask1 + (size_t)mB * CIN;

    floatx4 acc0[8], acc1[8];
#pragma unroll
    for (int t = 0; t < 8; t++) {
        acc0[t] = (floatx4){0.f, 0.f, 0.f, 0.f};
        acc1[t] = (floatx4){0.f, 0.f, 0.f, 0.f};
    }

#pragma unroll
    for (int ks = 0; ks < 8; ks++) {
        const int k0 = ks * 32 + kgrp * 8;
        floatx4 a0 = *(const floatx4*)(ea + k0);
        floatx4 a1 = *(const floatx4*)(ea + k0 + 4);
        floatx4 p0 = *(const floatx4*)(qa + k0);
        floatx4 p1 = *(const floatx4*)(qa + k0 + 4);
        floatx4 c0 = *(const floatx4*)(eb + k0);
        floatx4 c1 = *(const floatx4*)(eb + k0 + 4);
        floatx4 d0 = *(const floatx4*)(qb + k0);
        floatx4 d1 = *(const floatx4*)(qb + k0 + 4);
        bf16x8 x0, x1;
#pragma unroll
        for (int j = 0; j < 4; j++) {
            x0[j]     = (__bf16)(a0[j] * p0[j]);
            x0[4 + j] = (__bf16)(a1[j] * p1[j]);
            x1[j]     = (__bf16)(c0[j] * d0[j]);
            x1[4 + j] = (__bf16)(c1[j] * d1[j]);
        }
        const __bf16* bp = wlds + ((size_t)ks * 8 * 64 + lane) * 8;
#pragma unroll
        for (int t = 0; t < 8; t++) {
            bf16x8 b = *(const bf16x8*)(bp + (size_t)t * 512);
            acc0[t] = __builtin_amdgcn_mfma_f32_16x16x32_bf16(x0, b, acc0[t], 0, 0, 0);
            acc1[t] = __builtin_amdgcn_mfma_f32_16x16x32_bf16(x1, b, acc1[t], 0, 0, 0);
        }
    }

#pragma unroll
    for (int t = 0; t < 8; t++) {
        const int col = t * 16 + mrow;
        const float bc = b_fc[col];
#pragma unroll
        for (int r = 0; r < 4; r++) {
            const int row0 = m0 + kgrp * 4 + r;
            const int row1 = m0 + 16 + kgrp * 4 + r;
            if (row0 < NROWS)
                feat[(size_t)row0 * COUT + col] = (__bf16)(acc0[t][r] + bc);
            if (row1 < NROWS)
                feat[(size_t)row1 * COUT + col] = (__bf16)(acc1[t][r] + bc);
        }
    }
}

// ---------------------------------------------------------------------------
// Kernel 2: histogram of rows -> counts[]
// ---------------------------------------------------------------------------
__global__ __launch_bounds__(256) void hist_kernel(
    const int* __restrict__ rows, int* __restrict__ counts)
{
    const int i = blockIdx.x * 256 + threadIdx.x;
    if (i < NEDGE) atomicAdd(&counts[rows[i]], 1);
}

// ---------------------------------------------------------------------------
// Kernels 3a/3b/3c: hierarchical exclusive scan of counts -> row_start
// (bsum has a DEDICATED ws slot — no aliasing with edge.)
// ---------------------------------------------------------------------------
__global__ __launch_bounds__(1024) void scan1_kernel(
    const int* __restrict__ counts, int* __restrict__ row_start,
    int* __restrict__ bsum)
{
    __shared__ int s[1024];
    const int t = threadIdx.x;
    const int i = blockIdx.x * 1024 + t;
    const int v = (i < NROWS) ? counts[i] : 0;
    s[t] = v;
    __syncthreads();
    for (int off = 1; off < 1024; off <<= 1) {
        int u = (t >= off) ? s[t - off] : 0;
        __syncthreads();
        s[t] += u;
        __syncthreads();
    }
    if (i < NROWS) row_start[i] = s[t] - v;   // exclusive within block
    if (t == 1023) bsum[blockIdx.x] = s[1023];
}

__global__ __launch_bounds__(128) void scan2_kernel(int* __restrict__ bsum)
{
    __shared__ int s[128];
    const int t = threadIdx.x;
    const int NB = (NROWS + 1023) / 1024;   // 98
    const int v = (t < NB) ? bsum[t] : 0;
    s[t] = v;
    __syncthreads();
    for (int off = 1; off < 128; off <<= 1) {
        int u = (t >= off) ? s[t - off] : 0;
        __syncthreads();
        s[t] += u;
        __syncthreads();
    }
    if (t < NB) bsum[t] = s[t] - v;          // exclusive block offsets
}

__global__ __launch_bounds__(256) void scan3_kernel(
    int* __restrict__ row_start, const int* __restrict__ bsum)
{
    const int i = blockIdx.x * 256 + threadIdx.x;
    if (i < NROWS) row_start[i] += bsum[i >> 10];
}

// ---------------------------------------------------------------------------
// Kernel 4: scatter edges into CSR order as packed (col, val_bits) int2.
// row_start itself is the bump cursor: post-fill, row_start[r] == the
// ORIGINAL row_start[r+1]  (no separate cursor array, no extra memset).
// ---------------------------------------------------------------------------
__global__ __launch_bounds__(256) void fill_kernel(
    const int* __restrict__ rows, const int* __restrict__ cols,
    const float* __restrict__ vals,
    int* __restrict__ row_start, int2* __restrict__ edge)
{
    const int i = blockIdx.x * 256 + threadIdx.x;
    if (i < NEDGE) {
        const int r = rows[i];
        const int pos = atomicAdd(&row_start[r], 1);
        edge[pos] = make_int2(cols[i], __float_as_int(vals[i]));
    }
}

// ---------------------------------------------------------------------------
// Kernel 5: per-row gather-accumulate + fused epilogue (f32 out)
// Post-fill row_start semantics: seg(row) = [row? row_start[row-1] : 0,
// row_start[row]).  One wave per row; lane covers 2 adjacent cols; edge loop
// unrolled x4 with independent accumulators (round-3-validated shape).
// ---------------------------------------------------------------------------
__global__ __launch_bounds__(256) void gather_kernel(
    const __bf16* __restrict__ feat, const int* __restrict__ row_start,
    const int2* __restrict__ edge,
    const float* __restrict__ bias, const float* __restrict__ mask2,
    const float* __restrict__ prelu_a, float* __restrict__ out)
{
    const int wave = threadIdx.x >> 6;
    const int lane = threadIdx.x & 63;
    const int row = blockIdx.x * 4 + wave;
    if (row >= NROWS) return;

    const int s = (row == 0) ? 0 : __builtin_amdgcn_readfirstlane(row_start[row - 1]);
    const int e = __builtin_amdgcn_readfirstlane(row_start[row]);
    const int c2 = lane * 2;

    float p0 = 0.f, p1 = 0.f, q0 = 0.f, q1 = 0.f;
    float r0 = 0.f, r1 = 0.f, u0 = 0.f, u1 = 0.f;
    int k = s;
    for (; k + 4 <= e; k += 4) {
        const int2 e0 = edge[k],     e1 = edge[k + 1];
        const int2 e2 = edge[k + 2], e3 = edge[k + 3];
        bf16x2 h0 = *(const bf16x2*)(feat + (size_t)e0.x * COUT + c2);
        bf16x2 h1 = *(const bf16x2*)(feat + (size_t)e1.x * COUT + c2);
        bf16x2 h2 = *(const bf16x2*)(feat + (size_t)e2.x * COUT + c2);
        bf16x2 h3 = *(const bf16x2*)(feat + (size_t)e3.x * COUT + c2);
        const float v0 = __int_as_float(e0.y), v1 = __int_as_float(e1.y);
        const float v2 = __int_as_float(e2.y), v3 = __int_as_float(e3.y);
        p0 += v0 * (float)h0[0]; p1 += v0 * (float)h0[1];
        q0 += v1 * (float)h1[0]; q1 += v1 * (float)h1[1];
        r0 += v2 * (float)h2[0]; r1 += v2 * (float)h2[1];
        u0 += v3 * (float)h3[0]; u1 += v3 * (float)h3[1];
    }
    for (; k < e; k++) {
        const int2 e0 = edge[k];
        bf16x2 h0 = *(const bf16x2*)(feat + (size_t)e0.x * COUT + c2);
        const float v0 = __int_as_float(e0.y);
        p0 += v0 * (float)h0[0]; p1 += v0 * (float)h0[1];
    }
    const float acc0 = (p0 + q0) + (r0 + u0);
    const float acc1 = (p1 + q1) + (r1 + u1);

    const float a = prelu_a[0];
    floatx2 b = *(const floatx2*)(bias + c2);
    floatx2 m = *(const floatx2*)(mask2 + (size_t)row * COUT + c2);
    float o0 = (acc0 + b[0]) * m[0];
    float o1 = (acc1 + b[1]) * m[1];
    o0 = (o0 > 0.f) ? o0 : a * o0;
    o1 = (o1 > 0.f) ? o1 : a * o1;
    floatx2 o;
    o[0] = o0;
    o[1] = o1;
    *(floatx2*)(out + (size_t)row * COUT + c2) = o;
}

// ---------------------------------------------------------------------------
extern "C" void kernel_launch(void* const* d_in, const int* in_sizes, int n_in,
                              void* d_out, int out_size, void* d_ws, size_t ws_size,
                              hipStream_t stream)
{
    const float* emb     = (const float*)d_in[0];
    const float* vals    = (const float*)d_in[1];
    const float* W       = (const float*)d_in[2];
    const float* b_fc    = (const float*)d_in[3];
    const float* bias    = (const float*)d_in[4];
    const float* prelu_a = (const float*)d_in[5];
    const float* mask1   = (const float*)d_in[6];
    const float* mask2   = (const float*)d_in[7];
    const int*   rows    = (const int*)d_in[8];
    const int*   cols    = (const int*)d_in[9];

    char* ws = (char*)d_ws;
    // ws layout (disjoint, 16B-aligned), total 39,200,512 B
    __bf16* feat      = (__bf16*)(ws);                       // 25,600,000 B
    int*    counts    = (int*)(ws + 25600000);               //    400,000 B
    int*    row_start = (int*)(ws + 26000000);               //    400,000 B
    int*    bsum      = (int*)(ws + 26400000);               //        512 B
    int2*   edge      = (int2*)(ws + 26400512);              // 12,800,000 B

    // zero counts only (row_start fully written by scan1; no cursor array)
    hipMemsetAsync(counts, 0, 400000, stream);

    gemm_kernel<<<(NROWS + 127) / 128, 256, 0, stream>>>(emb, mask1, W, b_fc, feat);
    hist_kernel<<<NEDGE / 256, 256, 0, stream>>>(rows, counts);
    scan1_kernel<<<(NROWS + 1023) / 1024, 1024, 0, stream>>>(counts, row_start, bsum);
    scan2_kernel<<<1, 128, 0, stream>>>(bsum);
    scan3_kernel<<<(NROWS + 255) / 256, 256, 0, stream>>>(row_start, bsum);
    fill_kernel<<<NEDGE / 256, 256, 0, stream>>>(rows, cols, vals, row_start, edge);
    gather_kernel<<<NROWS / 4, 256, 0, stream>>>(feat, row_start, edge,
                                                 bias, mask2, prelu_a,
                                                 (float*)d_out);
}

// Round 6
// 500.396 us; speedup vs baseline: 1.7151x; 1.1618x over previous
//
#include <hip/hip_runtime.h>
#include <hip/hip_bf16.h>

#define NROWS 100000
#define NEDGE 1600000
#define CIN   256
#define COUT  128
#define SENT  0x1FFFFF   // 21-bit all-ones: list terminator in the next-field

typedef __bf16 bf16x8 __attribute__((ext_vector_type(8)));
typedef __bf16 bf16x4 __attribute__((ext_vector_type(4)));
typedef float  floatx4 __attribute__((ext_vector_type(4)));

// ---------------------------------------------------------------------------
// Kernel 1: feat = (emb .* mask1) @ W^T + b_fc      [NROWS x COUT]
// (unchanged from round 5 — validated)
// W staged ONCE per block into LDS as bf16 in fragment-major layout:
//   frag(ks,t), lane l  ->  wlds[((ks*8+t)*64 + l)*8 .. +8]   (64 KB total)
// Every B-fragment read is a stride-1 ds_read_b128 (conflict-free).
// Each wave: 32 rows (2 A-frags) x 128 cols; block = 4 waves = 128 rows.
// A-frag: A[m=lane&15][k=(lane>>4)*8+j]; C/D: col=lane&15, row=(lane>>4)*4+reg
// ---------------------------------------------------------------------------
__global__ __launch_bounds__(256) void gemm_kernel(
    const float* __restrict__ emb, const float* __restrict__ mask1,
    const float* __restrict__ W,   const float* __restrict__ b_fc,
    __bf16* __restrict__ feat)
{
    __shared__ __bf16 wlds[32768];   // 64 KB exactly

    const int tid = threadIdx.x;

    // --- stage W (f32 -> bf16, fragment-major), 16 frags per thread ---
#pragma unroll
    for (int f = tid; f < 4096; f += 256) {
        const int g    = f >> 6;       // ks*8 + t
        const int l8   = f & 63;       // lane within frag
        const int ks   = g >> 3;
        const int t    = g & 7;
        const int mr   = l8 & 15;
        const int kg   = l8 >> 4;
        const float* wp = W + (size_t)(t * 16 + mr) * CIN + ks * 32 + kg * 8;
        floatx4 w0 = *(const floatx4*)(wp);
        floatx4 w1 = *(const floatx4*)(wp + 4);
        bf16x8 b;
#pragma unroll
        for (int j = 0; j < 4; j++) {
            b[j]     = (__bf16)w0[j];
            b[4 + j] = (__bf16)w1[j];
        }
        *(bf16x8*)(wlds + (size_t)f * 8) = b;
    }
    __syncthreads();

    const int wave = tid >> 6;
    const int lane = tid & 63;
    const int mrow = lane & 15;
    const int kgrp = lane >> 4;
    const int m0 = blockIdx.x * 128 + wave * 32;

    int mA = m0 + mrow;
    int mB = m0 + 16 + mrow;
    if (mA >= NROWS) mA = NROWS - 1;   // clamp loads; stores guarded
    if (mB >= NROWS) mB = NROWS - 1;
    const float* ea = emb   + (size_t)mA * CIN;
    const float* qa = mask1 + (size_t)mA * CIN;
    const float* eb = emb   + (size_t)mB * CIN;
    const float* qb = mask1 + (size_t)mB * CIN;

    floatx4 acc0[8], acc1[8];
#pragma unroll
    for (int t = 0; t < 8; t++) {
        acc0[t] = (floatx4){0.f, 0.f, 0.f, 0.f};
        acc1[t] = (floatx4){0.f, 0.f, 0.f, 0.f};
    }

#pragma unroll
    for (int ks = 0; ks < 8; ks++) {
        const int k0 = ks * 32 + kgrp * 8;
        floatx4 a0 = *(const floatx4*)(ea + k0);
        floatx4 a1 = *(const floatx4*)(ea + k0 + 4);
        floatx4 p0 = *(const floatx4*)(qa + k0);
        floatx4 p1 = *(const floatx4*)(qa + k0 + 4);
        floatx4 c0 = *(const floatx4*)(eb + k0);
        floatx4 c1 = *(const floatx4*)(eb + k0 + 4);
        floatx4 d0 = *(const floatx4*)(qb + k0);
        floatx4 d1 = *(const floatx4*)(qb + k0 + 4);
        bf16x8 x0, x1;
#pragma unroll
        for (int j = 0; j < 4; j++) {
            x0[j]     = (__bf16)(a0[j] * p0[j]);
            x0[4 + j] = (__bf16)(a1[j] * p1[j]);
            x1[j]     = (__bf16)(c0[j] * d0[j]);
            x1[4 + j] = (__bf16)(c1[j] * d1[j]);
        }
        const __bf16* bp = wlds + ((size_t)ks * 8 * 64 + lane) * 8;
#pragma unroll
        for (int t = 0; t < 8; t++) {
            bf16x8 b = *(const bf16x8*)(bp + (size_t)t * 512);
            acc0[t] = __builtin_amdgcn_mfma_f32_16x16x32_bf16(x0, b, acc0[t], 0, 0, 0);
            acc1[t] = __builtin_amdgcn_mfma_f32_16x16x32_bf16(x1, b, acc1[t], 0, 0, 0);
        }
    }

#pragma unroll
    for (int t = 0; t < 8; t++) {
        const int col = t * 16 + mrow;
        const float bc = b_fc[col];
#pragma unroll
        for (int r = 0; r < 4; r++) {
            const int row0 = m0 + kgrp * 4 + r;
            const int row1 = m0 + 16 + kgrp * 4 + r;
            if (row0 < NROWS)
                feat[(size_t)row0 * COUT + col] = (__bf16)(acc0[t][r] + bc);
            if (row1 < NROWS)
                feat[(size_t)row1 * COUT + col] = (__bf16)(acc1[t][r] + bc);
        }
    }
}

// ---------------------------------------------------------------------------
// Kernel 2: build per-row linked lists (replaces hist+scan+fill).
// head[r] = last edge index for row r (-1 = empty, via 0xFF memset).
// next2[i] packs {next:21b | col_lo:11b} , {col_hi:6b | val15:15b}:
//   .x = next | (col & 0x7FF) << 21
//   .y = (col >> 11) | (v15 << 6)        v15 = round(val * 32767), val in [0,1)
// Stores to next2 are COALESCED (index i); only the 4B atomicExch is random,
// into a 400 KB L2-resident array -> no 64B write-allocate waste.
// ---------------------------------------------------------------------------
__global__ __launch_bounds__(256) void build_kernel(
    const int* __restrict__ rows, const int* __restrict__ cols,
    const float* __restrict__ vals,
    int* __restrict__ head, int2* __restrict__ next2)
{
    const int i = blockIdx.x * 256 + threadIdx.x;
    if (i < NEDGE) {
        const int r = rows[i];
        const int c = cols[i];
        const int v15 = (int)(vals[i] * 32767.0f + 0.5f);
        const int old = atomicExch(&head[r], i);
        const int nf = old & SENT;               // -1 -> SENT
        next2[i] = make_int2(nf | ((c & 0x7FF) << 21),
                             (c >> 11) | (v15 << 6));
    }
}

// ---------------------------------------------------------------------------
// Kernel 3: per-row chain-walk gather + fused epilogue (f32 out).
// Half-wave (32 lanes) per row, 4 cols/lane (bf16x4 feat loads, floatx4 out).
// Critical dep chain per hop is just next2[e] -> e; feat loads are off-chain.
// Rows with different chain lengths coexist via exec-masking (__any loop).
// ---------------------------------------------------------------------------
__global__ __launch_bounds__(256) void gather_kernel(
    const __bf16* __restrict__ feat, const int* __restrict__ head,
    const int2* __restrict__ next2,
    const float* __restrict__ bias, const float* __restrict__ mask2,
    const float* __restrict__ prelu_a, float* __restrict__ out)
{
    const int tid  = threadIdx.x;
    const int wave = tid >> 6;
    const int lane = tid & 63;
    const int half = lane >> 5;            // 0/1: which row of the pair
    const int l32  = lane & 31;
    const int row  = blockIdx.x * 8 + wave * 2 + half;   // grid exact: 12500*8
    const int c4   = l32 * 4;

    int e = head[row];                      // uniform within the half-wave
    float a0 = 0.f, a1 = 0.f, a2 = 0.f, a3 = 0.f;

    while (__any(e != -1)) {
        if (e != -1) {
            const int2 p = next2[e];
            const int nf  = p.x & SENT;
            const int col = ((p.x >> 21) & 0x7FF) | ((p.y & 0x3F) << 11);
            const float v = (float)(p.y >> 6) * (1.0f / 32767.0f);
            bf16x4 h = *(const bf16x4*)(feat + (size_t)col * COUT + c4);
            a0 += v * (float)h[0];
            a1 += v * (float)h[1];
            a2 += v * (float)h[2];
            a3 += v * (float)h[3];
            e = (nf == SENT) ? -1 : nf;
        }
    }

    const float pa = prelu_a[0];
    floatx4 b = *(const floatx4*)(bias + c4);
    floatx4 m = *(const floatx4*)(mask2 + (size_t)row * COUT + c4);
    floatx4 o;
    float t0 = (a0 + b[0]) * m[0];
    float t1 = (a1 + b[1]) * m[1];
    float t2 = (a2 + b[2]) * m[2];
    float t3 = (a3 + b[3]) * m[3];
    o[0] = (t0 > 0.f) ? t0 : pa * t0;
    o[1] = (t1 > 0.f) ? t1 : pa * t1;
    o[2] = (t2 > 0.f) ? t2 : pa * t2;
    o[3] = (t3 > 0.f) ? t3 : pa * t3;
    *(floatx4*)(out + (size_t)row * COUT + c4) = o;
}

// ---------------------------------------------------------------------------
extern "C" void kernel_launch(void* const* d_in, const int* in_sizes, int n_in,
                              void* d_out, int out_size, void* d_ws, size_t ws_size,
                              hipStream_t stream)
{
    const float* emb     = (const float*)d_in[0];
    const float* vals    = (const float*)d_in[1];
    const float* W       = (const float*)d_in[2];
    const float* b_fc    = (const float*)d_in[3];
    const float* bias    = (const float*)d_in[4];
    const float* prelu_a = (const float*)d_in[5];
    const float* mask1   = (const float*)d_in[6];
    const float* mask2   = (const float*)d_in[7];
    const int*   rows    = (const int*)d_in[8];
    const int*   cols    = (const int*)d_in[9];

    char* ws = (char*)d_ws;
    // ws layout (disjoint, 16B-aligned), total 38,800,000 B
    __bf16* feat  = (__bf16*)(ws);                 // 25,600,000 B
    int*    head  = (int*)(ws + 25600000);         //    400,000 B
    int2*   next2 = (int2*)(ws + 26000000);        // 12,800,000 B

    hipMemsetAsync(head, 0xFF, 400000, stream);    // head[r] = -1

    build_kernel<<<NEDGE / 256, 256, 0, stream>>>(rows, cols, vals, head, next2);
    gemm_kernel<<<(NROWS + 127) / 128, 256, 0, stream>>>(emb, mask1, W, b_fc, feat);
    gather_kernel<<<NROWS / 8, 256, 0, stream>>>(feat, head, next2,
                                                 bias, mask2, prelu_a,
                                                 (float*)d_out);
}

// Round 7
// 465.159 us; speedup vs baseline: 1.8450x; 1.0758x over previous
//
#include <hip/hip_runtime.h>
#include <hip/hip_bf16.h>

#define NROWS 100000
#define NEDGE 1600000
#define CIN   256
#define COUT  128
#define SENT  0x1FFFFF   // 21-bit all-ones: list terminator in the next-field

typedef __bf16 bf16x8 __attribute__((ext_vector_type(8)));
typedef float  floatx4 __attribute__((ext_vector_type(4)));

// ---------------------------------------------------------------------------
// Kernel 1: feat = (emb .* mask1) @ W^T + b_fc      [NROWS x COUT]
// Same validated math as round 5/6; block widened to 512 thr (8 waves,
// 256 rows) so 2 blocks/CU (LDS-capped) now gives 4 waves/SIMD not 2.
// W staged ONCE per block into LDS as bf16, fragment-major:
//   frag(ks,t), lane l -> wlds[((ks*8+t)*64 + l)*8 .. +8]   (64 KB)
// A-frag: A[m=lane&15][k=(lane>>4)*8+j]; C/D: col=lane&15, row=(lane>>4)*4+reg
// ---------------------------------------------------------------------------
__global__ __launch_bounds__(512) void gemm_kernel(
    const float* __restrict__ emb, const float* __restrict__ mask1,
    const float* __restrict__ W,   const float* __restrict__ b_fc,
    __bf16* __restrict__ feat)
{
    __shared__ __bf16 wlds[32768];   // 64 KB exactly

    const int tid = threadIdx.x;

    // --- stage W (f32 -> bf16, fragment-major), 8 frags per thread ---
#pragma unroll
    for (int f = tid; f < 4096; f += 512) {
        const int g    = f >> 6;       // ks*8 + t
        const int l8   = f & 63;       // lane within frag
        const int ks   = g >> 3;
        const int t    = g & 7;
        const int mr   = l8 & 15;
        const int kg   = l8 >> 4;
        const float* wp = W + (size_t)(t * 16 + mr) * CIN + ks * 32 + kg * 8;
        floatx4 w0 = *(const floatx4*)(wp);
        floatx4 w1 = *(const floatx4*)(wp + 4);
        bf16x8 b;
#pragma unroll
        for (int j = 0; j < 4; j++) {
            b[j]     = (__bf16)w0[j];
            b[4 + j] = (__bf16)w1[j];
        }
        *(bf16x8*)(wlds + (size_t)f * 8) = b;
    }
    __syncthreads();

    const int wave = tid >> 6;          // 0..7
    const int lane = tid & 63;
    const int mrow = lane & 15;
    const int kgrp = lane >> 4;
    const int m0 = blockIdx.x * 256 + wave * 32;

    int mA = m0 + mrow;
    int mB = m0 + 16 + mrow;
    if (mA >= NROWS) mA = NROWS - 1;   // clamp loads; stores guarded
    if (mB >= NROWS) mB = NROWS - 1;
    const float* ea = emb   + (size_t)mA * CIN;
    const float* qa = mask1 + (size_t)mA * CIN;
    const float* eb = emb   + (size_t)mB * CIN;
    const float* qb = mask1 + (size_t)mB * CIN;

    floatx4 acc0[8], acc1[8];
#pragma unroll
    for (int t = 0; t < 8; t++) {
        acc0[t] = (floatx4){0.f, 0.f, 0.f, 0.f};
        acc1[t] = (floatx4){0.f, 0.f, 0.f, 0.f};
    }

#pragma unroll
    for (int ks = 0; ks < 8; ks++) {
        const int k0 = ks * 32 + kgrp * 8;
        floatx4 a0 = *(const floatx4*)(ea + k0);
        floatx4 a1 = *(const floatx4*)(ea + k0 + 4);
        floatx4 p0 = *(const floatx4*)(qa + k0);
        floatx4 p1 = *(const floatx4*)(qa + k0 + 4);
        floatx4 c0 = *(const floatx4*)(eb + k0);
        floatx4 c1 = *(const floatx4*)(eb + k0 + 4);
        floatx4 d0 = *(const floatx4*)(qb + k0);
        floatx4 d1 = *(const floatx4*)(qb + k0 + 4);
        bf16x8 x0, x1;
#pragma unroll
        for (int j = 0; j < 4; j++) {
            x0[j]     = (__bf16)(a0[j] * p0[j]);
            x0[4 + j] = (__bf16)(a1[j] * p1[j]);
            x1[j]     = (__bf16)(c0[j] * d0[j]);
            x1[4 + j] = (__bf16)(c1[j] * d1[j]);
        }
        const __bf16* bp = wlds + ((size_t)ks * 8 * 64 + lane) * 8;
#pragma unroll
        for (int t = 0; t < 8; t++) {
            bf16x8 b = *(const bf16x8*)(bp + (size_t)t * 512);
            acc0[t] = __builtin_amdgcn_mfma_f32_16x16x32_bf16(x0, b, acc0[t], 0, 0, 0);
            acc1[t] = __builtin_amdgcn_mfma_f32_16x16x32_bf16(x1, b, acc1[t], 0, 0, 0);
        }
    }

#pragma unroll
    for (int t = 0; t < 8; t++) {
        const int col = t * 16 + mrow;
        const float bc = b_fc[col];
#pragma unroll
        for (int r = 0; r < 4; r++) {
            const int row0 = m0 + kgrp * 4 + r;
            const int row1 = m0 + 16 + kgrp * 4 + r;
            if (row0 < NROWS)
                feat[(size_t)row0 * COUT + col] = (__bf16)(acc0[t][r] + bc);
            if (row1 < NROWS)
                feat[(size_t)row1 * COUT + col] = (__bf16)(acc1[t][r] + bc);
        }
    }
}

// ---------------------------------------------------------------------------
// Kernel 2: build per-row linked lists (validated round 6, unchanged).
// head[r] = last edge index for row r (-1 = empty, via 0xFF memset).
// next2[i] packs {next:21b | col_lo:11b} , {col_hi:6b | val15:15b}
// ---------------------------------------------------------------------------
__global__ __launch_bounds__(256) void build_kernel(
    const int* __restrict__ rows, const int* __restrict__ cols,
    const float* __restrict__ vals,
    int* __restrict__ head, int2* __restrict__ next2)
{
    const int i = blockIdx.x * 256 + threadIdx.x;
    if (i < NEDGE) {
        const int r = rows[i];
        const int c = cols[i];
        const int v15 = (int)(vals[i] * 32767.0f + 0.5f);
        const int old = atomicExch(&head[r], i);
        const int nf = old & SENT;               // -1 -> SENT
        next2[i] = make_int2(nf | ((c & 0x7FF) << 21),
                             (c >> 11) | (v15 << 6));
    }
}

// ---------------------------------------------------------------------------
// Kernel 3: per-row chain-walk gather + fused epilogue (f32 out).
// QUARTER-wave (16 lanes) per row, 8 cols/lane (bf16x8 16B feat loads).
// 4 chains per wave -> 2x rows in flight vs round 6 (latency hiding).
// ---------------------------------------------------------------------------
__global__ __launch_bounds__(256) void gather_kernel(
    const __bf16* __restrict__ feat, const int* __restrict__ head,
    const int2* __restrict__ next2,
    const float* __restrict__ bias, const float* __restrict__ mask2,
    const float* __restrict__ prelu_a, float* __restrict__ out)
{
    const int tid  = threadIdx.x;
    const int wave = tid >> 6;
    const int lane = tid & 63;
    const int q    = lane >> 4;            // 0..3: which chain of the wave
    const int l16  = lane & 15;
    const int row  = blockIdx.x * 16 + wave * 4 + q;   // grid exact: 6250*16
    const int c8   = l16 * 8;

    int e = head[row];                      // uniform within the quarter-wave
    float a0 = 0.f, a1 = 0.f, a2 = 0.f, a3 = 0.f;
    float a4 = 0.f, a5 = 0.f, a6 = 0.f, a7 = 0.f;

    while (__any(e != -1)) {
        if (e != -1) {
            const int2 p = next2[e];
            const int nf  = p.x & SENT;
            const int col = ((p.x >> 21) & 0x7FF) | ((p.y & 0x3F) << 11);
            const float v = (float)(p.y >> 6) * (1.0f / 32767.0f);
            bf16x8 h = *(const bf16x8*)(feat + (size_t)col * COUT + c8);
            a0 += v * (float)h[0];
            a1 += v * (float)h[1];
            a2 += v * (float)h[2];
            a3 += v * (float)h[3];
            a4 += v * (float)h[4];
            a5 += v * (float)h[5];
            a6 += v * (float)h[6];
            a7 += v * (float)h[7];
            e = (nf == SENT) ? -1 : nf;
        }
    }

    const float pa = prelu_a[0];
    floatx4 b0 = *(const floatx4*)(bias + c8);
    floatx4 b1 = *(const floatx4*)(bias + c8 + 4);
    floatx4 m0 = *(const floatx4*)(mask2 + (size_t)row * COUT + c8);
    floatx4 m1 = *(const floatx4*)(mask2 + (size_t)row * COUT + c8 + 4);
    float t0 = (a0 + b0[0]) * m0[0];
    float t1 = (a1 + b0[1]) * m0[1];
    float t2 = (a2 + b0[2]) * m0[2];
    float t3 = (a3 + b0[3]) * m0[3];
    float t4 = (a4 + b1[0]) * m1[0];
    float t5 = (a5 + b1[1]) * m1[1];
    float t6 = (a6 + b1[2]) * m1[2];
    float t7 = (a7 + b1[3]) * m1[3];
    floatx4 o0, o1;
    o0[0] = (t0 > 0.f) ? t0 : pa * t0;
    o0[1] = (t1 > 0.f) ? t1 : pa * t1;
    o0[2] = (t2 > 0.f) ? t2 : pa * t2;
    o0[3] = (t3 > 0.f) ? t3 : pa * t3;
    o1[0] = (t4 > 0.f) ? t4 : pa * t4;
    o1[1] = (t5 > 0.f) ? t5 : pa * t5;
    o1[2] = (t6 > 0.f) ? t6 : pa * t6;
    o1[3] = (t7 > 0.f) ? t7 : pa * t7;
    *(floatx4*)(out + (size_t)row * COUT + c8)     = o0;
    *(floatx4*)(out + (size_t)row * COUT + c8 + 4) = o1;
}

// ---------------------------------------------------------------------------
extern "C" void kernel_launch(void* const* d_in, const int* in_sizes, int n_in,
                              void* d_out, int out_size, void* d_ws, size_t ws_size,
                              hipStream_t stream)
{
    const float* emb     = (const float*)d_in[0];
    const float* vals    = (const float*)d_in[1];
    const float* W       = (const float*)d_in[2];
    const float* b_fc    = (const float*)d_in[3];
    const float* bias    = (const float*)d_in[4];
    const float* prelu_a = (const float*)d_in[5];
    const float* mask1   = (const float*)d_in[6];
    const float* mask2   = (const float*)d_in[7];
    const int*   rows    = (const int*)d_in[8];
    const int*   cols    = (const int*)d_in[9];

    char* ws = (char*)d_ws;
    // ws layout (disjoint, 16B-aligned), total 38,800,000 B
    __bf16* feat  = (__bf16*)(ws);                 // 25,600,000 B
    int*    head  = (int*)(ws + 25600000);         //    400,000 B
    int2*   next2 = (int2*)(ws + 26000000);        // 12,800,000 B

    hipMemsetAsync(head, 0xFF, 400000, stream);    // head[r] = -1

    build_kernel<<<NEDGE / 256, 256, 0, stream>>>(rows, cols, vals, head, next2);
    gemm_kernel<<<(NROWS + 255) / 256, 512, 0, stream>>>(emb, mask1, W, b_fc, feat);
    gather_kernel<<<NROWS / 16, 256, 0, stream>>>(feat, head, next2,
                                                  bias, mask2, prelu_a,
                                                  (float*)d_out);
}